// Round 6
// baseline (182.631 us; speedup 1.0000x reference)
//
#include <hip/hip_runtime.h>
#include <cstddef>

#define B_   8
#define H_   96
#define W_   96
#define HW_  9216
#define PIX_ 73728

typedef __attribute__((ext_vector_type(8))) __bf16 bf16x8;
typedef __attribute__((ext_vector_type(4))) float floatx4;

// ws layout (byte offsets)
#define XT_OFF   0                          // bf16 NHWC x: PIX*64*2
#define WFM_OFF  (XT_OFF + PIX_*64*2)       // main W frags: 18*4*64*8 bf16
#define WFO_OFF  (WFM_OFF + 18*4*64*8*2)    // offs W frags: 18*2*64*8 bf16

#define MSTR 76                             // meta LDS stride per pixel (floats)

__device__ __forceinline__ unsigned short f2bf(float f) {
    unsigned u = __float_as_uint(f);
    return (unsigned short)((u + 0x7FFFu + ((u >> 16) & 1u)) >> 16);
}

// ---------------------------------------------------------------------------
// Fused pre-pass: blocks [0,1152) transpose NCHW f32 -> NHWC bf16 (vectorized);
// blocks [1152,1179) pack MFMA A-fragments.
__global__ __launch_bounds__(256) void k_pre(const float* __restrict__ x,
                                             const float* __restrict__ offw,
                                             const float* __restrict__ mw,
                                             const float* __restrict__ convw,
                                             unsigned short* __restrict__ xt,
                                             unsigned short* __restrict__ wfm,
                                             unsigned short* __restrict__ wfo) {
    __shared__ float tile[64 * 68];
    int blk = blockIdx.x;
    int t = threadIdx.x;
    if (blk < 1152) {
        int bb  = blk / 144;
        int sp0 = (blk % 144) * 64;
        int cL = t >> 4;               // 0..15
        int s4 = (t & 15) * 4;         // 0..60
        #pragma unroll
        for (int i = 0; i < 4; ++i) {
            int c = cL + i * 16;
            float4 v = *(const float4*)&x[(size_t)(bb * 64 + c) * HW_ + sp0 + s4];
            *(float4*)&tile[c * 68 + s4] = v;
        }
        __syncthreads();
        int s2 = t >> 2;               // 0..63
        int cg = (t & 3) * 16;         // 0,16,32,48
        unsigned vv[8];
        #pragma unroll
        for (int j = 0; j < 8; ++j) {
            float f0 = tile[(cg + 2 * j) * 68 + s2];
            float f1 = tile[(cg + 2 * j + 1) * 68 + s2];
            vv[j] = (unsigned)f2bf(f0) | ((unsigned)f2bf(f1) << 16);
        }
        uint4 p0 = make_uint4(vv[0], vv[1], vv[2], vv[3]);
        uint4 p1 = make_uint4(vv[4], vv[5], vv[6], vv[7]);
        unsigned short* dst = xt + (size_t)(bb * HW_ + sp0 + s2) * 64 + cg;
        *(uint4*)dst = p0;
        *(uint4*)(dst + 8) = p1;
        return;
    }
    int g = (blk - 1152) * 256 + t;
    if (g < 4608) {
        int lane = g & 63, mtks = g >> 6;
        int mt = mtks & 3, ks = mtks >> 2;
        int o = mt * 16 + (lane & 15), quad = lane >> 4;
        unsigned v[8];
        #pragma unroll
        for (int j = 0; j < 8; ++j) {
            int k = ks * 32 + quad * 8 + j;
            int tt = k / 64, c = k % 64;
            v[j] = f2bf(convw[(size_t)(o * 64 + c) * 9 + tt]);
        }
        uint4 pk;
        pk.x = v[0] | (v[1] << 16); pk.y = v[2] | (v[3] << 16);
        pk.z = v[4] | (v[5] << 16); pk.w = v[6] | (v[7] << 16);
        *(uint4*)(wfm + (size_t)g * 8) = pk;
    } else if (g < 4608 + 2304) {
        int g2 = g - 4608;
        int lane = g2 & 63, mtks = g2 >> 6;
        int mt = mtks & 1, ks = mtks >> 1;
        int m = mt * 16 + (lane & 15), quad = lane >> 4;
        unsigned v[8];
        #pragma unroll
        for (int j = 0; j < 8; ++j) {
            int k = ks * 32 + quad * 8 + j;
            int tt = k / 64, c = k % 64;
            float f = 0.f;
            if (m < 18)      f = offw[(size_t)(m * 64 + c) * 9 + tt];
            else if (m < 27) f = mw[(size_t)((m - 18) * 64 + c) * 9 + tt];
            v[j] = f2bf(f);
        }
        uint4 pk;
        pk.x = v[0] | (v[1] << 16); pk.y = v[2] | (v[3] << 16);
        pk.z = v[4] | (v[5] << 16); pk.w = v[6] | (v[7] << 16);
        *(uint4*)(wfo + (size_t)g2 * 8) = pk;
    }
}

// ---------------------------------------------------------------------------
// Fused deform-conv. 256-thread blocks = 4 independent 16-pixel waves covering
// 64 consecutive output pixels (>=256B per o-row: clean HBM writes).
// Per-wave LDS handoff, wave-synchronous, NO __syncthreads.
// Phase 3 feeds raw gathered corners to MFMA and applies bilinear weights to
// the f32 MFMA output per-lane (blend-after-MFMA).
__global__ __launch_bounds__(256, 4) void k_fused(const unsigned short* __restrict__ xt,
                                                  const unsigned short* __restrict__ wfo,
                                                  const unsigned short* __restrict__ wfm,
                                                  const float* __restrict__ offb,
                                                  const float* __restrict__ mb,
                                                  const float* __restrict__ convb,
                                                  float* __restrict__ out) {
    __shared__ float s_off[4][32 * 17];     // [wave][m][pix16] (+1 pad)
    __shared__ float s_meta[4][16 * MSTR];  // [wave][pix][n*8 words]
    int tid = threadIdx.x, blk = blockIdx.x;
    int w = tid >> 6, lane = tid & 63, col = lane & 15, quad = lane >> 4;
    int q8 = quad * 8;
    int b  = blk / 144;                     // 144 blocks (64 px each) per batch image
    int sb = (blk % 144) * 64 + w * 16;
    const unsigned short* xtb = xt + (size_t)b * HW_ * 64;
    int sp = sb + col, hh = sp / 96, ww = sp % 96;

    // ---- phase 1: offset/mod conv GEMM (M=32, K=576, N=16) ----
    floatx4 aoff0 = {0.f, 0.f, 0.f, 0.f}, aoff1 = {0.f, 0.f, 0.f, 0.f};
    #pragma unroll 1
    for (int t = 0; t < 9; ++t) {
        int dh = t / 3 - 1, dw = t % 3 - 1;
        int h2 = hh + dh, w2 = ww + dw;
        bool ok = ((unsigned)h2 < 96u) && ((unsigned)w2 < 96u);
        const unsigned short* pb = xtb + ((size_t)(h2 * 96 + w2) * 64 + q8);
        uint4 bv[2];
        bv[0] = ok ? *(const uint4*)(pb)      : make_uint4(0, 0, 0, 0);
        bv[1] = ok ? *(const uint4*)(pb + 32) : make_uint4(0, 0, 0, 0);
        #pragma unroll
        for (int ksl = 0; ksl < 2; ++ksl) {
            int ks = t * 2 + ksl;
            bf16x8 a0 = *(const bf16x8*)(wfo + ((size_t)(ks * 2 + 0) * 64 + lane) * 8);
            bf16x8 a1 = *(const bf16x8*)(wfo + ((size_t)(ks * 2 + 1) * 64 + lane) * 8);
            union { uint4 u; bf16x8 b; } uu; uu.u = bv[ksl];
            aoff0 = __builtin_amdgcn_mfma_f32_16x16x32_bf16(a0, uu.b, aoff0, 0, 0, 0);
            aoff1 = __builtin_amdgcn_mfma_f32_16x16x32_bf16(a1, uu.b, aoff1, 0, 0, 0);
        }
    }
    #pragma unroll
    for (int r = 0; r < 4; ++r) {
        s_off[w][(quad * 4 + r) * 17 + col]        = aoff0[r];
        s_off[w][(16 + quad * 4 + r) * 17 + col]   = aoff1[r];
    }
    __builtin_amdgcn_wave_barrier();

    // ---- phase 2: bilinear metadata (wave-local; lane covers px=col, n set by quad) ----
    #pragma unroll
    for (int i = 0; i < 3; ++i) {
        int n = quad + 4 * i;
        if (n <= 8) {
            float ox = s_off[w][n * 17 + col]        + offb[n];
            float oy = s_off[w][(9 + n) * 17 + col]  + offb[9 + n];
            float mv = s_off[w][(18 + n) * 17 + col] + mb[n];
            float mod = 1.f / (1.f + __expf(-mv));
            float px = ox + (float)(hh + 1) + (float)(n / 3 - 1);
            float py = oy + (float)(ww + 1) + (float)(n % 3 - 1);
            float flx = floorf(px), fly = floorf(py);
            float tlxf = fminf(fmaxf(flx,       0.f), 97.f);
            float tlyf = fminf(fmaxf(fly,       0.f), 97.f);
            float brxf = fminf(fmaxf(flx + 1.f, 0.f), 97.f);
            float bryf = fminf(fmaxf(fly + 1.f, 0.f), 97.f);
            float pcx  = fminf(fmaxf(px, 0.f), 97.f);
            float pcy  = fminf(fmaxf(py, 0.f), 97.f);
            float gx0 = 1.f + tlxf - pcx;
            float gx1 = 1.f - (brxf - pcx);
            float gy0 = 1.f + tlyf - pcy;
            float gy1 = 1.f - (bryf - pcy);
            int tlx = (int)tlxf, tly = (int)tlyf, brx = (int)brxf, bry = (int)bryf;
            int   qxs[4] = {tlx, tlx, brx, brx};
            int   qys[4] = {tly, bry, tly, bry};
            float gs[4]  = {gx0 * gy0, gx0 * gy1, gx1 * gy0, gx1 * gy1};
            int   idx[4]; float gg[4];
            #pragma unroll
            for (int c4 = 0; c4 < 4; ++c4) {
                bool okc = (qxs[c4] >= 1) && (qxs[c4] <= 96) && (qys[c4] >= 1) && (qys[c4] <= 96);
                idx[c4] = okc ? ((qxs[c4] - 1) * W_ + (qys[c4] - 1)) : 0;
                gg[c4]  = okc ? gs[c4] * mod : 0.f;
            }
            int4 iv;   iv.x = idx[0]; iv.y = idx[1]; iv.z = idx[2]; iv.w = idx[3];
            float4 gv; gv.x = gg[0];  gv.y = gg[1];  gv.z = gg[2];  gv.w = gg[3];
            *(int4*)  &s_meta[w][col * MSTR + n * 8]     = iv;
            *(float4*)&s_meta[w][col * MSTR + n * 8 + 4] = gv;
        }
    }
    __builtin_amdgcn_wave_barrier();

    // ---- phase 3: main GEMM, blend-after-MFMA ----
    floatx4 acc[4];
    #pragma unroll
    for (int mt = 0; mt < 4; ++mt) acc[mt] = (floatx4){0.f, 0.f, 0.f, 0.f};
    const floatx4 ZF = {0.f, 0.f, 0.f, 0.f};

    #pragma unroll 1
    for (int n = 0; n < 9; ++n) {
        int4   idx = *(const int4*)  &s_meta[w][col * MSTR + n * 8];
        float4 g4  = *(const float4*)&s_meta[w][col * MSTR + n * 8 + 4];
        bf16x8 af[4][2];
        #pragma unroll
        for (int mt = 0; mt < 4; ++mt)
            #pragma unroll
            for (int ksl = 0; ksl < 2; ++ksl)
                af[mt][ksl] = *(const bf16x8*)(wfm + ((size_t)((n * 2 + ksl) * 4 + mt) * 64 + lane) * 8);
        int   ixs[4] = {idx.x, idx.y, idx.z, idx.w};
        float gws[4] = {g4.x, g4.y, g4.z, g4.w};
        #pragma unroll
        for (int q = 0; q < 4; ++q) {
            const unsigned short* pq = xtb + (size_t)ixs[q] * 64 + q8;
            bf16x8 b0 = *(const bf16x8*)(pq);
            bf16x8 b1 = *(const bf16x8*)(pq + 32);
            floatx4 Y[4];
            #pragma unroll
            for (int mt = 0; mt < 4; ++mt)
                Y[mt] = __builtin_amdgcn_mfma_f32_16x16x32_bf16(af[mt][0], b0, ZF, 0, 0, 0);
            #pragma unroll
            for (int mt = 0; mt < 4; ++mt)
                Y[mt] = __builtin_amdgcn_mfma_f32_16x16x32_bf16(af[mt][1], b1, Y[mt], 0, 0, 0);
            float gq = gws[q];
            #pragma unroll
            for (int mt = 0; mt < 4; ++mt)
                #pragma unroll
                for (int r = 0; r < 4; ++r)
                    acc[mt][r] = fmaf(gq, Y[mt][r], acc[mt][r]);
        }
    }

    // ---- epilogue: block writes 64 consecutive px per o-row (256 B, clean) ----
    #pragma unroll
    for (int mt = 0; mt < 4; ++mt) {
        float4 cb4 = *(const float4*)&convb[mt * 16 + quad * 4];
        #pragma unroll
        for (int r = 0; r < 4; ++r) {
            int o = mt * 16 + quad * 4 + r;
            float bias = (r == 0) ? cb4.x : (r == 1) ? cb4.y : (r == 2) ? cb4.z : cb4.w;
            out[(size_t)(b * 64 + o) * HW_ + sb + col] = acc[mt][r] + bias;
        }
    }
}

// ---------------------------------------------------------------------------
extern "C" void kernel_launch(void* const* d_in, const int* in_sizes, int n_in,
                              void* d_out, int out_size, void* d_ws, size_t ws_size,
                              hipStream_t stream) {
    const float* x     = (const float*)d_in[0];
    const float* offw  = (const float*)d_in[1];
    const float* offb  = (const float*)d_in[2];
    const float* mw    = (const float*)d_in[3];
    const float* mb    = (const float*)d_in[4];
    const float* convw = (const float*)d_in[5];
    const float* convb = (const float*)d_in[6];
    char* ws = (char*)d_ws;
    unsigned short* xt16 = (unsigned short*)(ws + XT_OFF);
    unsigned short* wfm  = (unsigned short*)(ws + WFM_OFF);
    unsigned short* wfo  = (unsigned short*)(ws + WFO_OFF);
    float* out = (float*)d_out;

    k_pre  <<<dim3(1179), dim3(256), 0, stream>>>(x, offw, mw, convw, xt16, wfm, wfo);
    k_fused<<<dim3(1152), dim3(256), 0, stream>>>(xt16, wfo, wfm, offb, mb, convb, out);
}

// Round 7
// 177.937 us; speedup vs baseline: 1.0264x; 1.0264x over previous
//
#include <hip/hip_runtime.h>
#include <cstddef>

#define B_   8
#define H_   96
#define W_   96
#define HW_  9216
#define PIX_ 73728

typedef __attribute__((ext_vector_type(8))) __bf16 bf16x8;
typedef __attribute__((ext_vector_type(4))) float floatx4;

// ws layout (byte offsets)
#define XT_OFF   0                          // bf16 NHWC x: PIX*64*2
#define WFM_OFF  (XT_OFF + PIX_*64*2)       // main W frags: 18*4*64*8 bf16
#define WFO_OFF  (WFM_OFF + 18*4*64*8*2)    // offs W frags: 18*2*64*8 bf16

#define MSTR 76                             // meta LDS stride per pixel (floats, 16B-aligned)

__device__ __forceinline__ unsigned short f2bf(float f) {
    unsigned u = __float_as_uint(f);
    return (unsigned short)((u + 0x7FFFu + ((u >> 16) & 1u)) >> 16);
}

// ---------------------------------------------------------------------------
// Fused pre-pass: blocks [0,1152) transpose NCHW f32 -> NHWC bf16 (vectorized);
// blocks [1152,1179) pack MFMA A-fragments.
__global__ __launch_bounds__(256) void k_pre(const float* __restrict__ x,
                                             const float* __restrict__ offw,
                                             const float* __restrict__ mw,
                                             const float* __restrict__ convw,
                                             unsigned short* __restrict__ xt,
                                             unsigned short* __restrict__ wfm,
                                             unsigned short* __restrict__ wfo) {
    __shared__ float tile[64 * 68];
    int blk = blockIdx.x;
    int t = threadIdx.x;
    if (blk < 1152) {
        int bb  = blk / 144;
        int sp0 = (blk % 144) * 64;
        int cL = t >> 4;               // 0..15
        int s4 = (t & 15) * 4;         // 0..60
        #pragma unroll
        for (int i = 0; i < 4; ++i) {
            int c = cL + i * 16;
            float4 v = *(const float4*)&x[(size_t)(bb * 64 + c) * HW_ + sp0 + s4];
            *(float4*)&tile[c * 68 + s4] = v;
        }
        __syncthreads();
        int s2 = t >> 2;               // 0..63
        int cg = (t & 3) * 16;         // 0,16,32,48
        unsigned vv[8];
        #pragma unroll
        for (int j = 0; j < 8; ++j) {
            float f0 = tile[(cg + 2 * j) * 68 + s2];
            float f1 = tile[(cg + 2 * j + 1) * 68 + s2];
            vv[j] = (unsigned)f2bf(f0) | ((unsigned)f2bf(f1) << 16);
        }
        uint4 p0 = make_uint4(vv[0], vv[1], vv[2], vv[3]);
        uint4 p1 = make_uint4(vv[4], vv[5], vv[6], vv[7]);
        unsigned short* dst = xt + (size_t)(bb * HW_ + sp0 + s2) * 64 + cg;
        *(uint4*)dst = p0;
        *(uint4*)(dst + 8) = p1;
        return;
    }
    int g = (blk - 1152) * 256 + t;
    if (g < 4608) {
        int lane = g & 63, mtks = g >> 6;
        int mt = mtks & 3, ks = mtks >> 2;
        int o = mt * 16 + (lane & 15), quad = lane >> 4;
        unsigned v[8];
        #pragma unroll
        for (int j = 0; j < 8; ++j) {
            int k = ks * 32 + quad * 8 + j;
            int tt = k / 64, c = k % 64;
            v[j] = f2bf(convw[(size_t)(o * 64 + c) * 9 + tt]);
        }
        uint4 pk;
        pk.x = v[0] | (v[1] << 16); pk.y = v[2] | (v[3] << 16);
        pk.z = v[4] | (v[5] << 16); pk.w = v[6] | (v[7] << 16);
        *(uint4*)(wfm + (size_t)g * 8) = pk;
    } else if (g < 4608 + 2304) {
        int g2 = g - 4608;
        int lane = g2 & 63, mtks = g2 >> 6;
        int mt = mtks & 1, ks = mtks >> 1;
        int m = mt * 16 + (lane & 15), quad = lane >> 4;
        unsigned v[8];
        #pragma unroll
        for (int j = 0; j < 8; ++j) {
            int k = ks * 32 + quad * 8 + j;
            int tt = k / 64, c = k % 64;
            float f = 0.f;
            if (m < 18)      f = offw[(size_t)(m * 64 + c) * 9 + tt];
            else if (m < 27) f = mw[(size_t)((m - 18) * 64 + c) * 9 + tt];
            v[j] = f2bf(f);
        }
        uint4 pk;
        pk.x = v[0] | (v[1] << 16); pk.y = v[2] | (v[3] << 16);
        pk.z = v[4] | (v[5] << 16); pk.w = v[6] | (v[7] << 16);
        *(uint4*)(wfo + (size_t)g2 * 8) = pk;
    }
}

// ---------------------------------------------------------------------------
// Fused deform-conv, O-split: block = 128 thr = 2 waves over the SAME 32 px.
// Wave w computes output channels o in [32w, 32w+32): every output 128B line
// (32 px * 4B) is fully written by ONE wave in adjacent instructions (clean
// HBM writes — the r5/r6 WRITE-amplification fix). Phases 1-2 are split
// across the 2 waves and shared via LDS (2 __syncthreads); phase 3 waves are
// fully independent. Blend-after-MFMA: raw gathered corners feed MFMA,
// bilinear weights applied to the f32 result per-lane.
__global__ __launch_bounds__(128, 4) void k_fused(const unsigned short* __restrict__ xt,
                                                  const unsigned short* __restrict__ wfo,
                                                  const unsigned short* __restrict__ wfm,
                                                  const float* __restrict__ offb,
                                                  const float* __restrict__ mb,
                                                  const float* __restrict__ convb,
                                                  float* __restrict__ out) {
    __shared__ float s_off[32 * 33];        // [m][px32] (+1 pad)
    __shared__ float s_meta[32 * MSTR];     // [px][n*8 words]
    int tid = threadIdx.x, blk = blockIdx.x;
    int w = tid >> 6, lane = tid & 63, col = lane & 15, quad = lane >> 4;
    int q8 = quad * 8;
    int b  = blk / 288;                     // 288 blocks (32 px each) per batch image
    int sb = (blk % 288) * 32;              // 32 px, 128B-aligned output lines
    const unsigned short* xtb = xt + (size_t)b * HW_ * 64;

    int sj[2], hj[2], wj[2];
    #pragma unroll
    for (int jj = 0; jj < 2; ++jj) {
        sj[jj] = sb + jj * 16 + col;
        hj[jj] = sj[jj] / 96; wj[jj] = sj[jj] % 96;
    }

    // ---- phase 1: offset/mod conv GEMM (M=32 split by wave: m-tile = w) ----
    floatx4 aoff[2] = {{0.f, 0.f, 0.f, 0.f}, {0.f, 0.f, 0.f, 0.f}};
    #pragma unroll 1
    for (int t = 0; t < 9; ++t) {
        int dh = t / 3 - 1, dw = t % 3 - 1;
        uint4 bv[2][2];
        #pragma unroll
        for (int jj = 0; jj < 2; ++jj) {
            int h2 = hj[jj] + dh, w2 = wj[jj] + dw;
            bool ok = ((unsigned)h2 < 96u) && ((unsigned)w2 < 96u);
            const unsigned short* pb = xtb + ((size_t)(h2 * 96 + w2) * 64 + q8);
            bv[jj][0] = ok ? *(const uint4*)(pb)      : make_uint4(0, 0, 0, 0);
            bv[jj][1] = ok ? *(const uint4*)(pb + 32) : make_uint4(0, 0, 0, 0);
        }
        #pragma unroll
        for (int ksl = 0; ksl < 2; ++ksl) {
            int ks = t * 2 + ksl;
            bf16x8 a = *(const bf16x8*)(wfo + ((size_t)(ks * 2 + w) * 64 + lane) * 8);
            #pragma unroll
            for (int jj = 0; jj < 2; ++jj) {
                union { uint4 u; bf16x8 b; } uu; uu.u = bv[jj][ksl];
                aoff[jj] = __builtin_amdgcn_mfma_f32_16x16x32_bf16(a, uu.b, aoff[jj], 0, 0, 0);
            }
        }
    }
    #pragma unroll
    for (int jj = 0; jj < 2; ++jj)
        #pragma unroll
        for (int r = 0; r < 4; ++r)
            s_off[(w * 16 + quad * 4 + r) * 33 + jj * 16 + col] = aoff[jj][r];
    __syncthreads();

    // ---- phase 2: bilinear metadata (n split by wave: w0 -> 0..4, w1 -> 5..8) ----
    {
        int gl = lane >> 5;                 // 0..1
        int pp = lane & 31;
        int sP = sb + pp, hh = sP / 96, ww = sP % 96;
        int nb = w ? 5 : 0, ne = w ? 9 : 5;
        for (int n = nb + gl; n < ne; n += 2) {
            float ox = s_off[n * 33 + pp]        + offb[n];
            float oy = s_off[(9 + n) * 33 + pp]  + offb[9 + n];
            float mv = s_off[(18 + n) * 33 + pp] + mb[n];
            float mod = 1.f / (1.f + __expf(-mv));
            float px = ox + (float)(hh + 1) + (float)(n / 3 - 1);
            float py = oy + (float)(ww + 1) + (float)(n % 3 - 1);
            float flx = floorf(px), fly = floorf(py);
            float tlxf = fminf(fmaxf(flx,       0.f), 97.f);
            float tlyf = fminf(fmaxf(fly,       0.f), 97.f);
            float brxf = fminf(fmaxf(flx + 1.f, 0.f), 97.f);
            float bryf = fminf(fmaxf(fly + 1.f, 0.f), 97.f);
            float pcx  = fminf(fmaxf(px, 0.f), 97.f);
            float pcy  = fminf(fmaxf(py, 0.f), 97.f);
            float gx0 = 1.f + tlxf - pcx;
            float gx1 = 1.f - (brxf - pcx);
            float gy0 = 1.f + tlyf - pcy;
            float gy1 = 1.f - (bryf - pcy);
            int tlx = (int)tlxf, tly = (int)tlyf, brx = (int)brxf, bry = (int)bryf;
            int   qxs[4] = {tlx, tlx, brx, brx};
            int   qys[4] = {tly, bry, tly, bry};
            float gs[4]  = {gx0 * gy0, gx0 * gy1, gx1 * gy0, gx1 * gy1};
            int   idx[4]; float gg[4];
            #pragma unroll
            for (int c4 = 0; c4 < 4; ++c4) {
                bool okc = (qxs[c4] >= 1) && (qxs[c4] <= 96) && (qys[c4] >= 1) && (qys[c4] <= 96);
                idx[c4] = okc ? ((qxs[c4] - 1) * W_ + (qys[c4] - 1)) : 0;
                gg[c4]  = okc ? gs[c4] * mod : 0.f;
            }
            int4 iv;   iv.x = idx[0]; iv.y = idx[1]; iv.z = idx[2]; iv.w = idx[3];
            float4 gv; gv.x = gg[0];  gv.y = gg[1];  gv.z = gg[2];  gv.w = gg[3];
            *(int4*)  &s_meta[pp * MSTR + n * 8]     = iv;
            *(float4*)&s_meta[pp * MSTR + n * 8 + 4] = gv;
        }
    }
    __syncthreads();

    // ---- phase 3: main GEMM (o-tile per wave), blend-after-MFMA, no barriers ----
    floatx4 acc[2][2];                      // [jj][mtL]
    #pragma unroll
    for (int jj = 0; jj < 2; ++jj)
        #pragma unroll
        for (int mtL = 0; mtL < 2; ++mtL) acc[jj][mtL] = (floatx4){0.f, 0.f, 0.f, 0.f};
    const floatx4 ZF = {0.f, 0.f, 0.f, 0.f};

    #pragma unroll 1
    for (int n = 0; n < 9; ++n) {
        int4 idx[2]; float4 g4[2];
        #pragma unroll
        for (int jj = 0; jj < 2; ++jj) {
            int mo = (jj * 16 + col) * MSTR + n * 8;
            idx[jj] = *(const int4*)  &s_meta[mo];
            g4[jj]  = *(const float4*)&s_meta[mo + 4];
        }
        bf16x8 af[2][2];                    // [mtL][ksl]
        #pragma unroll
        for (int mtL = 0; mtL < 2; ++mtL)
            #pragma unroll
            for (int ksl = 0; ksl < 2; ++ksl)
                af[mtL][ksl] = *(const bf16x8*)(wfm + ((size_t)((n * 2 + ksl) * 4 + (w * 2 + mtL)) * 64 + lane) * 8);
        #pragma unroll
        for (int jj = 0; jj < 2; ++jj) {
            int   ixs[4] = {idx[jj].x, idx[jj].y, idx[jj].z, idx[jj].w};
            float gws[4] = {g4[jj].x, g4[jj].y, g4[jj].z, g4[jj].w};
            #pragma unroll
            for (int q = 0; q < 4; ++q) {
                const unsigned short* pq = xtb + (size_t)ixs[q] * 64 + q8;
                bf16x8 b0 = *(const bf16x8*)(pq);
                bf16x8 b1 = *(const bf16x8*)(pq + 32);
                floatx4 Y0 = __builtin_amdgcn_mfma_f32_16x16x32_bf16(af[0][0], b0, ZF, 0, 0, 0);
                floatx4 Y1 = __builtin_amdgcn_mfma_f32_16x16x32_bf16(af[1][0], b0, ZF, 0, 0, 0);
                Y0 = __builtin_amdgcn_mfma_f32_16x16x32_bf16(af[0][1], b1, Y0, 0, 0, 0);
                Y1 = __builtin_amdgcn_mfma_f32_16x16x32_bf16(af[1][1], b1, Y1, 0, 0, 0);
                float gq = gws[q];
                #pragma unroll
                for (int r = 0; r < 4; ++r) {
                    acc[jj][0][r] = fmaf(gq, Y0[r], acc[jj][0][r]);
                    acc[jj][1][r] = fmaf(gq, Y1[r], acc[jj][1][r]);
                }
            }
        }
    }

    // ---- epilogue: wave w writes o in [32w,32w+32); full 128B line per o-row ----
    #pragma unroll
    for (int mtL = 0; mtL < 2; ++mtL) {
        #pragma unroll
        for (int r = 0; r < 4; ++r) {
            int o = w * 32 + mtL * 16 + quad * 4 + r;
            float bias = convb[o];
            #pragma unroll
            for (int jj = 0; jj < 2; ++jj)
                out[(size_t)(b * 64 + o) * HW_ + sj[jj]] = acc[jj][mtL][r] + bias;
        }
    }
}

// ---------------------------------------------------------------------------
extern "C" void kernel_launch(void* const* d_in, const int* in_sizes, int n_in,
                              void* d_out, int out_size, void* d_ws, size_t ws_size,
                              hipStream_t stream) {
    const float* x     = (const float*)d_in[0];
    const float* offw  = (const float*)d_in[1];
    const float* offb  = (const float*)d_in[2];
    const float* mw    = (const float*)d_in[3];
    const float* mb    = (const float*)d_in[4];
    const float* convw = (const float*)d_in[5];
    const float* convb = (const float*)d_in[6];
    char* ws = (char*)d_ws;
    unsigned short* xt16 = (unsigned short*)(ws + XT_OFF);
    unsigned short* wfm  = (unsigned short*)(ws + WFM_OFF);
    unsigned short* wfo  = (unsigned short*)(ws + WFO_OFF);
    float* out = (float*)d_out;

    k_pre  <<<dim3(1179), dim3(256), 0, stream>>>(x, offw, mw, convw, xt16, wfm, wfo);
    k_fused<<<dim3(2304), dim3(128), 0, stream>>>(xt16, wfo, wfm, offb, mb, convb, out);
}

// Round 8
// 151.514 us; speedup vs baseline: 1.2054x; 1.1744x over previous
//
#include <hip/hip_runtime.h>
#include <cstddef>

#define B_   8
#define H_   96
#define W_   96
#define HW_  9216
#define PIX_ 73728

typedef __attribute__((ext_vector_type(8))) __bf16 bf16x8;
typedef __attribute__((ext_vector_type(4))) float floatx4;

// ws layout (byte offsets)
#define XT_OFF   0                          // bf16 NHWC x: PIX*64*2
#define WFM_OFF  (XT_OFF + PIX_*64*2)       // main W frags: 18*4*64*8 bf16
#define WFO_OFF  (WFM_OFF + 18*4*64*8*2)    // offs W frags: 18*2*64*8 bf16

// LDS overlay (bytes). WIN: 270 rowpx * 72 shorts (144B stride) = 38880
// SOFF: 32*50 f32 = 6400 ; SIDX: 48*40 short = 3840 ; SG: 48*40 f32 = 7680
// SOUT (64*52 f32 = 13312) overlays SOFF+SIDX+part of SG after phase 3.
#define L_WIN   0
#define L_SOFF  38880
#define L_SIDX  45280
#define L_SG    49120
#define L_TOTAL 56800
#define L_SOUT  38880

__device__ __forceinline__ unsigned short f2bf(float f) {
    unsigned u = __float_as_uint(f);
    return (unsigned short)((u + 0x7FFFu + ((u >> 16) & 1u)) >> 16);
}

// ---------------------------------------------------------------------------
// Pre-pass: blocks [0,1152) transpose NCHW f32 -> NHWC bf16; [1152,1179) pack
// MFMA A-fragments (k = tap*64 + c).
__global__ __launch_bounds__(256) void k_pre(const float* __restrict__ x,
                                             const float* __restrict__ offw,
                                             const float* __restrict__ mw,
                                             const float* __restrict__ convw,
                                             unsigned short* __restrict__ xt,
                                             unsigned short* __restrict__ wfm,
                                             unsigned short* __restrict__ wfo) {
    __shared__ float tile[64 * 68];
    int blk = blockIdx.x;
    int t = threadIdx.x;
    if (blk < 1152) {
        int bb  = blk / 144;
        int sp0 = (blk % 144) * 64;
        int cL = t >> 4;
        int s4 = (t & 15) * 4;
        #pragma unroll
        for (int i = 0; i < 4; ++i) {
            int c = cL + i * 16;
            float4 v = *(const float4*)&x[(size_t)(bb * 64 + c) * HW_ + sp0 + s4];
            *(float4*)&tile[c * 68 + s4] = v;
        }
        __syncthreads();
        int s2 = t >> 2;
        int cg = (t & 3) * 16;
        unsigned vv[8];
        #pragma unroll
        for (int j = 0; j < 8; ++j) {
            float f0 = tile[(cg + 2 * j) * 68 + s2];
            float f1 = tile[(cg + 2 * j + 1) * 68 + s2];
            vv[j] = (unsigned)f2bf(f0) | ((unsigned)f2bf(f1) << 16);
        }
        uint4 p0 = make_uint4(vv[0], vv[1], vv[2], vv[3]);
        uint4 p1 = make_uint4(vv[4], vv[5], vv[6], vv[7]);
        unsigned short* dst = xt + (size_t)(bb * HW_ + sp0 + s2) * 64 + cg;
        *(uint4*)dst = p0;
        *(uint4*)(dst + 8) = p1;
        return;
    }
    int g = (blk - 1152) * 256 + t;
    if (g < 4608) {
        int lane = g & 63, mtks = g >> 6;
        int mt = mtks & 3, ks = mtks >> 2;
        int o = mt * 16 + (lane & 15), quad = lane >> 4;
        unsigned v[8];
        #pragma unroll
        for (int j = 0; j < 8; ++j) {
            int k = ks * 32 + quad * 8 + j;
            int tt = k / 64, c = k % 64;
            v[j] = f2bf(convw[(size_t)(o * 64 + c) * 9 + tt]);
        }
        uint4 pk;
        pk.x = v[0] | (v[1] << 16); pk.y = v[2] | (v[3] << 16);
        pk.z = v[4] | (v[5] << 16); pk.w = v[6] | (v[7] << 16);
        *(uint4*)(wfm + (size_t)g * 8) = pk;
    } else if (g < 4608 + 2304) {
        int g2 = g - 4608;
        int lane = g2 & 63, mtks = g2 >> 6;
        int mt = mtks & 1, ks = mtks >> 1;
        int m = mt * 16 + (lane & 15), quad = lane >> 4;
        unsigned v[8];
        #pragma unroll
        for (int j = 0; j < 8; ++j) {
            int k = ks * 32 + quad * 8 + j;
            int tt = k / 64, c = k % 64;
            float f = 0.f;
            if (m < 18)      f = offw[(size_t)(m * 64 + c) * 9 + tt];
            else if (m < 27) f = mw[(size_t)((m - 18) * 64 + c) * 9 + tt];
            v[j] = f2bf(f);
        }
        uint4 pk;
        pk.x = v[0] | (v[1] << 16); pk.y = v[2] | (v[3] << 16);
        pk.z = v[4] | (v[5] << 16); pk.w = v[6] | (v[7] << 16);
        *(uint4*)(wfo + (size_t)g2 * 8) = pk;
    }
}

// ---------------------------------------------------------------------------
// Fused deform-conv with LDS window staging (im2col-style dedup).
// Block = 48 px of one image row (b, h, w0). 384 thr = 6 waves:
// wave = (p = px-chunk of 16, oh = o-half). Window = rows[h-2..h+2] x
// cols[w0-3..w0+50], bf16, 144-B stride, zeros outside image.
// Phase1 conv + phase3 gathers read the window via ds_read_b128; rare
// out-of-window corners (|off|>~1) take a global-gather fallback per n.
__global__ __launch_bounds__(384, 3) void k_fused(const unsigned short* __restrict__ xt,
                                                  const unsigned short* __restrict__ wfo,
                                                  const unsigned short* __restrict__ wfm,
                                                  const float* __restrict__ offb,
                                                  const float* __restrict__ mb,
                                                  const float* __restrict__ convb,
                                                  float* __restrict__ out) {
    __shared__ __align__(16) char smem[L_TOTAL];
    unsigned short* WIN = (unsigned short*)(smem + L_WIN);
    float* SOFF = (float*)(smem + L_SOFF);
    short* SIDX = (short*)(smem + L_SIDX);
    float* SG   = (float*)(smem + L_SG);
    float* SOUT = (float*)(smem + L_SOUT);

    int tid = threadIdx.x, blk = blockIdx.x;
    int half = blk & 1, rid = blk >> 1;
    int b = rid / 96, h = rid % 96;
    int w0 = half * 48;
    int wv = tid >> 6, lane = tid & 63, col = lane & 15, quad = lane >> 4;
    int p = wv % 3, oh = wv / 3;
    int lp = p * 16 + col;
    const unsigned short* xtb = xt + (size_t)b * HW_ * 64;

    // ---- phase 0: stage the window (coalesced; zeros outside image) ----
    #pragma unroll
    for (int k = 0; k < 6; ++k) {
        int i = tid + k * 384;
        if (i < 2160) {
            int rowpx = i >> 3, part = i & 7;
            int wx = rowpx / 54, wy = rowpx - wx * 54;
            int xx = h - 2 + wx, yy = w0 - 3 + wy;
            uint4 v = make_uint4(0, 0, 0, 0);
            if ((unsigned)xx < 96u && (unsigned)yy < 96u)
                v = *(const uint4*)(xtb + (size_t)(xx * 96 + yy) * 64 + part * 8);
            *(uint4*)(WIN + rowpx * 72 + part * 8) = v;
        }
    }
    __syncthreads();

    // ---- phase 1: offset/mod conv GEMM from LDS (wave does m-tile = oh) ----
    {
        floatx4 aoff = {0.f, 0.f, 0.f, 0.f};
        #pragma unroll 1
        for (int t = 0; t < 9; ++t) {
            int dh = t / 3 - 1, dw = t % 3 - 1;
            int rowpx = (dh + 2) * 54 + (lp + dw + 3);
            const unsigned short* bp = WIN + rowpx * 72 + quad * 8;
            bf16x8 b0 = *(const bf16x8*)bp;
            bf16x8 b1 = *(const bf16x8*)(bp + 32);
            bf16x8 a0 = *(const bf16x8*)(wfo + ((size_t)((2 * t + 0) * 2 + oh) * 64 + lane) * 8);
            bf16x8 a1 = *(const bf16x8*)(wfo + ((size_t)((2 * t + 1) * 2 + oh) * 64 + lane) * 8);
            aoff = __builtin_amdgcn_mfma_f32_16x16x32_bf16(a0, b0, aoff, 0, 0, 0);
            aoff = __builtin_amdgcn_mfma_f32_16x16x32_bf16(a1, b1, aoff, 0, 0, 0);
        }
        #pragma unroll
        for (int r = 0; r < 4; ++r)
            SOFF[(oh * 16 + quad * 4 + r) * 50 + lp] = aoff[r];
    }
    __syncthreads();

    // ---- phase 2: bilinear metadata (window idx or flagged global idx) ----
    {
        auto doMeta = [&](int n) {
            float ox = SOFF[n * 50 + lp]        + offb[n];
            float oy = SOFF[(9 + n) * 50 + lp]  + offb[9 + n];
            float mv = SOFF[(18 + n) * 50 + lp] + mb[n];
            float mod = 1.f / (1.f + __expf(-mv));
            float px = ox + (float)(h + 1) + (float)(n / 3 - 1);
            float py = oy + (float)(w0 + lp + 1) + (float)(n % 3 - 1);
            float flx = floorf(px), fly = floorf(py);
            float tlxf = fminf(fmaxf(flx,       0.f), 97.f);
            float tlyf = fminf(fmaxf(fly,       0.f), 97.f);
            float brxf = fminf(fmaxf(flx + 1.f, 0.f), 97.f);
            float bryf = fminf(fmaxf(fly + 1.f, 0.f), 97.f);
            float pcx  = fminf(fmaxf(px, 0.f), 97.f);
            float pcy  = fminf(fmaxf(py, 0.f), 97.f);
            float gx0 = 1.f + tlxf - pcx;
            float gx1 = 1.f - (brxf - pcx);
            float gy0 = 1.f + tlyf - pcy;
            float gy1 = 1.f - (bryf - pcy);
            int tlx = (int)tlxf, tly = (int)tlyf, brx = (int)brxf, bry = (int)bryf;
            int   qxs[4] = {tlx, tlx, brx, brx};
            int   qys[4] = {tly, bry, tly, bry};
            float gs[4]  = {gx0 * gy0, gx0 * gy1, gx1 * gy0, gx1 * gy1};
            short idxs[4]; float gg[4];
            #pragma unroll
            for (int c4 = 0; c4 < 4; ++c4) {
                bool okc = (qxs[c4] >= 1) && (qxs[c4] <= 96) && (qys[c4] >= 1) && (qys[c4] <= 96);
                gg[c4] = okc ? gs[c4] * mod : 0.f;
                short ivv = 0;
                if (okc) {
                    int x0 = qxs[c4] - 1, y0 = qys[c4] - 1;
                    int wx = x0 - h + 2, wy = y0 - w0 + 3;
                    if ((unsigned)wx < 5u && (unsigned)wy < 54u)
                        ivv = (short)(wx * 54 + wy);
                    else
                        ivv = (short)(-(x0 * 96 + y0) - 1);
                }
                idxs[c4] = ivv;
            }
            short4 sv; sv.x = idxs[0]; sv.y = idxs[1]; sv.z = idxs[2]; sv.w = idxs[3];
            *(short4*)&SIDX[lp * 40 + n * 4] = sv;
            float4 gv; gv.x = gg[0]; gv.y = gg[1]; gv.z = gg[2]; gv.w = gg[3];
            *(float4*)&SG[lp * 40 + n * 4] = gv;
        };
        if (oh == 0) { doMeta(quad); if (quad == 0) doMeta(8); }
        else         { doMeta(4 + quad); }
    }
    __syncthreads();

    // ---- phase 3: main GEMM (o-half per wave), gathers from LDS window ----
    floatx4 acc0 = {0.f, 0.f, 0.f, 0.f}, acc1 = {0.f, 0.f, 0.f, 0.f};
    const floatx4 ZF = {0.f, 0.f, 0.f, 0.f};
    #pragma unroll 1
    for (int n = 0; n < 9; ++n) {
        short4 iv = *(const short4*)&SIDX[lp * 40 + n * 4];
        float4 gv = *(const float4*)&SG[lp * 40 + n * 4];
        bf16x8 af00 = *(const bf16x8*)(wfm + ((size_t)((2 * n + 0) * 4 + 2 * oh + 0) * 64 + lane) * 8);
        bf16x8 af10 = *(const bf16x8*)(wfm + ((size_t)((2 * n + 0) * 4 + 2 * oh + 1) * 64 + lane) * 8);
        bf16x8 af01 = *(const bf16x8*)(wfm + ((size_t)((2 * n + 1) * 4 + 2 * oh + 0) * 64 + lane) * 8);
        bf16x8 af11 = *(const bf16x8*)(wfm + ((size_t)((2 * n + 1) * 4 + 2 * oh + 1) * 64 + lane) * 8);
        int   ivs[4] = {iv.x, iv.y, iv.z, iv.w};
        float gs4[4] = {gv.x, gv.y, gv.z, gv.w};
        int mn = min(min(ivs[0], ivs[1]), min(ivs[2], ivs[3]));
        if (!__any(mn < 0)) {
            #pragma unroll
            for (int q = 0; q < 4; ++q) {
                const unsigned short* bp = WIN + ivs[q] * 72 + quad * 8;
                bf16x8 b0 = *(const bf16x8*)bp;
                bf16x8 b1 = *(const bf16x8*)(bp + 32);
                floatx4 Y0 = __builtin_amdgcn_mfma_f32_16x16x32_bf16(af00, b0, ZF, 0, 0, 0);
                floatx4 Y1 = __builtin_amdgcn_mfma_f32_16x16x32_bf16(af10, b0, ZF, 0, 0, 0);
                Y0 = __builtin_amdgcn_mfma_f32_16x16x32_bf16(af01, b1, Y0, 0, 0, 0);
                Y1 = __builtin_amdgcn_mfma_f32_16x16x32_bf16(af11, b1, Y1, 0, 0, 0);
                float gq = gs4[q];
                #pragma unroll
                for (int r = 0; r < 4; ++r) {
                    acc0[r] = fmaf(gq, Y0[r], acc0[r]);
                    acc1[r] = fmaf(gq, Y1[r], acc1[r]);
                }
            }
        } else {
            // rare fallback: gather rows from global (correctness unconditional)
            #pragma unroll
            for (int q = 0; q < 4; ++q) {
                int wq = ivs[q], gr;
                if (wq >= 0) {
                    int wx = wq / 54, wy = wq - wx * 54;
                    gr = (h - 2 + wx) * 96 + (w0 - 3 + wy);
                } else gr = -wq - 1;
                gr = min(max(gr, 0), HW_ - 1);
                const unsigned short* bp = xtb + (size_t)gr * 64 + quad * 8;
                bf16x8 b0 = *(const bf16x8*)bp;
                bf16x8 b1 = *(const bf16x8*)(bp + 32);
                floatx4 Y0 = __builtin_amdgcn_mfma_f32_16x16x32_bf16(af00, b0, ZF, 0, 0, 0);
                floatx4 Y1 = __builtin_amdgcn_mfma_f32_16x16x32_bf16(af10, b0, ZF, 0, 0, 0);
                Y0 = __builtin_amdgcn_mfma_f32_16x16x32_bf16(af01, b1, Y0, 0, 0, 0);
                Y1 = __builtin_amdgcn_mfma_f32_16x16x32_bf16(af11, b1, Y1, 0, 0, 0);
                float gq = gs4[q];
                #pragma unroll
                for (int r = 0; r < 4; ++r) {
                    acc0[r] = fmaf(gq, Y0[r], acc0[r]);
                    acc1[r] = fmaf(gq, Y1[r], acc1[r]);
                }
            }
        }
    }
    __syncthreads();      // s_meta dead; SOUT overlay becomes safe

    // ---- epilogue: stage to LDS, then coalesced full-line global writes ----
    #pragma unroll
    for (int mtL = 0; mtL < 2; ++mtL) {
        #pragma unroll
        for (int r = 0; r < 4; ++r) {
            int o = (2 * oh + mtL) * 16 + quad * 4 + r;
            SOUT[o * 52 + lp] = (mtL == 0) ? acc0[r] : acc1[r];
        }
    }
    __syncthreads();
    {
        int o = tid / 6, seg = tid % 6;   // 64 o * 6 segs of 8 px
        float bias = convb[o];
        const float* src = &SOUT[o * 52 + seg * 8];
        float4 v0 = *(const float4*)(src);
        float4 v1 = *(const float4*)(src + 4);
        v0.x += bias; v0.y += bias; v0.z += bias; v0.w += bias;
        v1.x += bias; v1.y += bias; v1.z += bias; v1.w += bias;
        float* dst = out + (size_t)(b * 64 + o) * HW_ + h * 96 + w0 + seg * 8;
        *(float4*)dst = v0;
        *(float4*)(dst + 4) = v1;
    }
}

// ---------------------------------------------------------------------------
extern "C" void kernel_launch(void* const* d_in, const int* in_sizes, int n_in,
                              void* d_out, int out_size, void* d_ws, size_t ws_size,
                              hipStream_t stream) {
    const float* x     = (const float*)d_in[0];
    const float* offw  = (const float*)d_in[1];
    const float* offb  = (const float*)d_in[2];
    const float* mw    = (const float*)d_in[3];
    const float* mb    = (const float*)d_in[4];
    const float* convw = (const float*)d_in[5];
    const float* convb = (const float*)d_in[6];
    char* ws = (char*)d_ws;
    unsigned short* xt16 = (unsigned short*)(ws + XT_OFF);
    unsigned short* wfm  = (unsigned short*)(ws + WFM_OFF);
    unsigned short* wfo  = (unsigned short*)(ws + WFO_OFF);
    float* out = (float*)d_out;

    k_pre  <<<dim3(1179), dim3(256), 0, stream>>>(x, offw, mw, convw, xt16, wfm, wfo);
    k_fused<<<dim3(1536), dim3(384), 0, stream>>>(xt16, wfo, wfm, offb, mb, convb, out);
}